// Round 7
// baseline (34.877 us; speedup 1.0000x reference)
//
#include <hip/hip_runtime.h>
#include <hip/hip_bf16.h>

// Lie (SE3) cumulative B-spline evaluation, single fused kernel (K==64 path):
//  out[b,p,k] = T0 * exp(w0(t_k)*log01) * exp(w1*log12) * exp(w2*log23)
// K=64 = wavefront size, so (b,p) is wave-uniform: the 3 rel-logs are computed
// once per wave in lockstep. Quaternion composition; LDS-staged lane-contiguous
// non-temporal output stores.

__device__ __forceinline__ float frcp(float x) { return __builtin_amdgcn_rcpf(x); }

using f32x4 = __attribute__((ext_vector_type(4))) float;

struct Quat { float w, x, y, z; };

__device__ __forceinline__ void rel_log(const float* __restrict__ Ta,
                                        const float* __restrict__ Tb,
                                        float xi[6]) {
    float R[9];
#pragma unroll
    for (int i = 0; i < 3; ++i)
#pragma unroll
        for (int j = 0; j < 3; ++j)
            R[i * 3 + j] = Ta[0 * 4 + i] * Tb[0 * 4 + j] +
                           Ta[1 * 4 + i] * Tb[1 * 4 + j] +
                           Ta[2 * 4 + i] * Tb[2 * 4 + j];
    float dx = Tb[3] - Ta[3], dy = Tb[7] - Ta[7], dz = Tb[11] - Ta[11];
    float t0 = Ta[0] * dx + Ta[4] * dy + Ta[8] * dz;
    float t1 = Ta[1] * dx + Ta[5] * dy + Ta[9] * dz;
    float t2 = Ta[2] * dx + Ta[6] * dy + Ta[10] * dz;

    float tr = R[0] + R[4] + R[8];
    float cos_th = 0.5f * (tr - 1.0f);
    cos_th = fminf(fmaxf(cos_th, -1.0f + 1e-6f), 1.0f - 1e-6f);
    float th = acosf(cos_th);
    float s = sinf(th);
    float vx = 0.5f * (R[7] - R[5]);
    float vy = 0.5f * (R[2] - R[6]);
    float vz = 0.5f * (R[3] - R[1]);
    float f = th / s;
    float ox = f * vx, oy = f * vy, oz = f * vz;
    float th2 = th * th;
    float D;
    if (th < 0.05f)
        D = 1.0f / 12.0f + th2 / 720.0f;
    else
        D = 1.0f / th2 - (1.0f + cos_th) / (2.0f * th * s);

    float oo = ox * ox + oy * oy + oz * oz;
    float V00 = 1.0f + D * (ox * ox - oo);
    float V01 = 0.5f * oz + D * (ox * oy);
    float V02 = -0.5f * oy + D * (ox * oz);
    float V10 = -0.5f * oz + D * (ox * oy);
    float V11 = 1.0f + D * (oy * oy - oo);
    float V12 = 0.5f * ox + D * (oy * oz);
    float V20 = 0.5f * oy + D * (ox * oz);
    float V21 = -0.5f * ox + D * (oy * oz);
    float V22 = 1.0f + D * (oz * oz - oo);

    xi[0] = V00 * t0 + V01 * t1 + V02 * t2;
    xi[1] = V10 * t0 + V11 * t1 + V12 * t2;
    xi[2] = V20 * t0 + V21 * t1 + V22 * t2;
    xi[3] = ox; xi[4] = oy; xi[5] = oz;
}

// exp(w*xi) -> (quat, translation) with Rodrigues-form V application.
__device__ __forceinline__ void exp_qt(float wgt, const float* __restrict__ xi,
                                       Quat& q, float t[3]) {
    float nx = wgt * xi[0], ny = wgt * xi[1], nz = wgt * xi[2];
    float ox = wgt * xi[3], oy = wgt * xi[4], oz = wgt * xi[5];
    float th2 = ox * ox + oy * oy + oz * oz;
    bool small = th2 < 1e-8f;
    float th = sqrtf(th2);
    float rth = frcp(th);
    float sh, ch;
    __sincosf(0.5f * th, &sh, &ch);
    float rth2 = rth * rth;
    float sh2 = sh * sh;
    float sinth = 2.0f * sh * ch;
    float sfac = small ? 0.5f - th2 * (1.0f / 48.0f) : sh * rth;
    float B = small ? 0.5f - th2 * (1.0f / 24.0f) : (sh2 + sh2) * rth2;
    float C = small ? (1.0f / 6.0f) - th2 * (1.0f / 120.0f)
                    : (th - sinth) * rth2 * rth;
    q.w = ch; q.x = sfac * ox; q.y = sfac * oy; q.z = sfac * oz;
    float c1x = oy * nz - oz * ny;
    float c1y = oz * nx - ox * nz;
    float c1z = ox * ny - oy * nx;
    float c2x = oy * c1z - oz * c1y;
    float c2y = oz * c1x - ox * c1z;
    float c2z = ox * c1y - oy * c1x;
    t[0] = nx + B * c1x + C * c2x;
    t[1] = ny + B * c1y + C * c2y;
    t[2] = nz + B * c1z + C * c2z;
}

__device__ __forceinline__ Quat qmul(const Quat& a, const Quat& b) {
    Quat r;
    r.w = a.w * b.w - a.x * b.x - a.y * b.y - a.z * b.z;
    r.x = a.w * b.x + a.x * b.w + a.y * b.z - a.z * b.y;
    r.y = a.w * b.y - a.x * b.z + a.y * b.w + a.z * b.x;
    r.z = a.w * b.z + a.x * b.y - a.y * b.x + a.z * b.w;
    return r;
}

__device__ __forceinline__ void qrot(const Quat& q, const float v[3], float o[3]) {
    float ux = q.y * v[2] - q.z * v[1];
    float uy = q.z * v[0] - q.x * v[2];
    float uz = q.x * v[1] - q.y * v[0];
    float sx = q.w * ux + (q.y * uz - q.z * uy);
    float sy = q.w * uy + (q.z * ux - q.x * uz);
    float sz = q.w * uz + (q.x * uy - q.y * ux);
    o[0] = v[0] + 2.0f * sx;
    o[1] = v[1] + 2.0f * sy;
    o[2] = v[2] + 2.0f * sz;
}

__device__ __forceinline__ void q2m(const Quat& q, float M[9]) {
    float x2 = q.x + q.x, y2 = q.y + q.y, z2 = q.z + q.z;
    float xx = q.x * x2, yy = q.y * y2, zz = q.z * z2;
    float xy = q.x * y2, xz = q.x * z2, yz = q.y * z2;
    float wx = q.w * x2, wy = q.w * y2, wz = q.w * z2;
    M[0] = 1.0f - (yy + zz); M[1] = xy - wz;          M[2] = xz + wy;
    M[3] = xy + wz;          M[4] = 1.0f - (xx + zz); M[5] = yz - wx;
    M[6] = xz - wy;          M[7] = yz + wx;          M[8] = 1.0f - (xx + yy);
}

// Fused fast path: K == 64 (k = lane), (b,p) wave-uniform.
// Per-wave lockstep rel-log recompute; quat composition; LDS-staged
// lane-contiguous non-temporal stores.
__global__ void __launch_bounds__(256)
spline_fused_k64(const float* __restrict__ poses,
                 const float* __restrict__ timev,
                 float* __restrict__ out,
                 int n, int total) {
    __shared__ f32x4 lds4[768];  // rows 0..2 of 256 matrices (row 3 constant)

    int tid = threadIdx.x;
    int g = blockIdx.x * 256 + tid;
    bool fullBlock = (blockIdx.x + 1) * 256 <= total;
    bool active = g < total;

    f32x4 r0, r1, r2;
    if (active) {
        int k = g & 63;
        int bp = __builtin_amdgcn_readfirstlane(g >> 6);
        int P = n - 1;
        int p = bp % P;
        int b = bp / P;

        int i0 = max(p - 1, 0);
        int i2 = min(p + 1, n - 1);
        int i3 = min(p + 2, n - 1);
        const float* base = poses + (size_t)b * n * 16;
        const float* T0 = base + i0 * 16;
        const float* T1 = base + p * 16;
        const float* T2 = base + i2 * 16;
        const float* T3 = base + i3 * 16;

        // Wave-uniform (all lanes lockstep on same data).
        float xi01[6], xi12[6], xi23[6];
        rel_log(T0, T1, xi01);
        rel_log(T1, T2, xi12);
        rel_log(T2, T3, xi23);

        float tt = timev[k];
        float t2 = tt * tt, t3 = t2 * tt;
        float w0 = (5.0f + 3.0f * tt - 3.0f * t2 + t3) * (1.0f / 6.0f);
        float w1 = (1.0f + 3.0f * tt + 3.0f * t2 - 2.0f * t3) * (1.0f / 6.0f);
        float w2 = t3 * (1.0f / 6.0f);

        Quat qa, qb, qc;
        float ta[3], tb[3], tc[3];
        exp_qt(w0, xi01, qa, ta);
        exp_qt(w1, xi12, qb, tb);
        exp_qt(w2, xi23, qc, tc);

        Quat qabc = qmul(qmul(qa, qb), qc);

        float u[3], v[3];
        qrot(qb, tc, u);
        u[0] += tb[0]; u[1] += tb[1]; u[2] += tb[2];
        qrot(qa, u, v);
        v[0] += ta[0]; v[1] += ta[1]; v[2] += ta[2];

        float M[9];
        q2m(qabc, M);

        float o[12];
#pragma unroll
        for (int i = 0; i < 3; ++i) {
            float a0 = T0[4 * i + 0], a1 = T0[4 * i + 1], a2 = T0[4 * i + 2];
            o[4 * i + 0] = a0 * M[0] + a1 * M[3] + a2 * M[6];
            o[4 * i + 1] = a0 * M[1] + a1 * M[4] + a2 * M[7];
            o[4 * i + 2] = a0 * M[2] + a1 * M[5] + a2 * M[8];
            o[4 * i + 3] = T0[4 * i + 3] + a0 * v[0] + a1 * v[1] + a2 * v[2];
        }
        r0 = (f32x4){o[0], o[1], o[2], o[3]};
        r1 = (f32x4){o[4], o[5], o[6], o[7]};
        r2 = (f32x4){o[8], o[9], o[10], o[11]};
    }

    if (fullBlock) {
        // Stage rows into LDS (lane-contiguous, conflict-free: 8 phases/wave).
        lds4[0 * 256 + tid] = r0;
        lds4[1 * 256 + tid] = r1;
        lds4[2 * 256 + tid] = r2;
        __syncthreads();
        // Cooperative contiguous store: float4 q = i*256+tid of this block's
        // 16 KB tile; q belongs to matrix q>>2, row q&3. Row 3 is constant.
        f32x4* outb = (f32x4*)out + (size_t)blockIdx.x * 1024;
        int r = tid & 3;
        int a = tid >> 2;
        const f32x4 last = (f32x4){0.0f, 0.0f, 0.0f, 1.0f};
#pragma unroll
        for (int i = 0; i < 4; ++i) {
            f32x4 val = (r == 3) ? last : lds4[r * 256 + 64 * i + a];
            __builtin_nontemporal_store(val, &outb[i * 256 + tid]);
        }
    } else if (active) {
        f32x4* o4 = (f32x4*)(out + (size_t)g * 16);
        o4[0] = r0;
        o4[1] = r1;
        o4[2] = r2;
        o4[3] = (f32x4){0.0f, 0.0f, 0.0f, 1.0f};
    }
}

// Generic fallback (matrix form), any K.
__device__ __forceinline__ void se3_exp_scaled(float sc, const float xi[6],
                                               float R[9], float t[3]) {
    float nx = sc * xi[0], ny = sc * xi[1], nz = sc * xi[2];
    float ox = sc * xi[3], oy = sc * xi[4], oz = sc * xi[5];
    float th2 = ox * ox + oy * oy + oz * oz;
    float A, B, C;
    if (th2 < 1e-8f) {
        A = 1.0f - th2 * (1.0f / 6.0f);
        B = 0.5f - th2 * (1.0f / 24.0f);
        C = 1.0f / 6.0f - th2 * (1.0f / 120.0f);
    } else {
        float th = sqrtf(th2);
        float sn, cs;
        __sincosf(th, &sn, &cs);
        float r = frcp(th);
        float r2 = r * r;
        A = sn * r;
        B = (1.0f - cs) * r2;
        C = (th - sn) * r2 * r;
    }
    float xx = ox * ox, yy = oy * oy, zz = oz * oz;
    float xy = ox * oy, xz = ox * oz, yz = oy * oz;
    R[0] = 1.0f + B * (xx - th2);
    R[1] = B * xy - A * oz;
    R[2] = B * xz + A * oy;
    R[3] = B * xy + A * oz;
    R[4] = 1.0f + B * (yy - th2);
    R[5] = B * yz - A * ox;
    R[6] = B * xz - A * oy;
    R[7] = B * yz + A * ox;
    R[8] = 1.0f + B * (zz - th2);
    float V00 = 1.0f + C * (xx - th2);
    float V01 = C * xy - B * oz;
    float V02 = C * xz + B * oy;
    float V10 = C * xy + B * oz;
    float V11 = 1.0f + C * (yy - th2);
    float V12 = C * yz - B * ox;
    float V20 = C * xz - B * oy;
    float V21 = C * yz + B * ox;
    float V22 = 1.0f + C * (zz - th2);
    t[0] = V00 * nx + V01 * ny + V02 * nz;
    t[1] = V10 * nx + V11 * ny + V12 * nz;
    t[2] = V20 * nx + V21 * ny + V22 * nz;
}

__device__ __forceinline__ void compose(const float R1[9], const float t1[3],
                                        const float R2[9], const float t2[3],
                                        float Ro[9], float to[3]) {
#pragma unroll
    for (int i = 0; i < 3; ++i) {
#pragma unroll
        for (int j = 0; j < 3; ++j)
            Ro[i * 3 + j] = R1[i * 3 + 0] * R2[0 * 3 + j] +
                            R1[i * 3 + 1] * R2[1 * 3 + j] +
                            R1[i * 3 + 2] * R2[2 * 3 + j];
        to[i] = R1[i * 3 + 0] * t2[0] + R1[i * 3 + 1] * t2[1] +
                R1[i * 3 + 2] * t2[2] + t1[i];
    }
}

__global__ void __launch_bounds__(256)
lie_spline_mono(const float* __restrict__ poses,
                const float* __restrict__ timev,
                float* __restrict__ out,
                int n, int K, int total) {
    int g = blockIdx.x * blockDim.x + threadIdx.x;
    if (g >= total) return;
    int P = n - 1;
    int k = g % K;
    int bp = g / K;
    int p = bp % P;
    int b = bp / P;
    int i0 = max(p - 1, 0);
    int i1 = p;
    int i2 = min(p + 1, n - 1);
    int i3 = min(p + 2, n - 1);
    const float* base = poses + (size_t)b * n * 16;
    const float *T0 = base + i0 * 16, *T1 = base + i1 * 16;
    const float *T2 = base + i2 * 16, *T3 = base + i3 * 16;
    float xi01[6], xi12[6], xi23[6];
    rel_log(T0, T1, xi01);
    rel_log(T1, T2, xi12);
    rel_log(T2, T3, xi23);
    float t = timev[k];
    float t2 = t * t, t3 = t2 * t;
    float w0 = (5.0f + 3.0f * t - 3.0f * t2 + t3) * (1.0f / 6.0f);
    float w1 = (1.0f + 3.0f * t + 3.0f * t2 - 2.0f * t3) * (1.0f / 6.0f);
    float w2 = t3 * (1.0f / 6.0f);
    float Ra[9], ta[3], Rb[9], tb[3], Rc[9], tc[3];
    se3_exp_scaled(w0, xi01, Ra, ta);
    se3_exp_scaled(w1, xi12, Rb, tb);
    se3_exp_scaled(w2, xi23, Rc, tc);
    float R0[9] = {T0[0], T0[1], T0[2], T0[4], T0[5], T0[6], T0[8], T0[9], T0[10]};
    float p0[3] = {T0[3], T0[7], T0[11]};
    float Rx[9], tx[3], Ry[9], ty[3], Rz[9], tz[3];
    compose(R0, p0, Ra, ta, Rx, tx);
    compose(Rx, tx, Rb, tb, Ry, ty);
    compose(Ry, ty, Rc, tc, Rz, tz);
    float4* o4 = (float4*)(out + (size_t)g * 16);
    o4[0] = make_float4(Rz[0], Rz[1], Rz[2], tz[0]);
    o4[1] = make_float4(Rz[3], Rz[4], Rz[5], tz[1]);
    o4[2] = make_float4(Rz[6], Rz[7], Rz[8], tz[2]);
    o4[3] = make_float4(0.0f, 0.0f, 0.0f, 1.0f);
}

extern "C" void kernel_launch(void* const* d_in, const int* in_sizes, int n_in,
                              void* d_out, int out_size, void* d_ws, size_t ws_size,
                              hipStream_t stream) {
    const float* poses = (const float*)d_in[0];
    const float* timev = (const float*)d_in[1];
    float* out = (float*)d_out;

    int K = in_sizes[1];
    int S = in_sizes[0] / 16;            // B * n
    int Q = out_size / (16 * K);         // B * (n-1)
    int Bsz = S - Q;                     // B
    int n = S / Bsz;

    int P = n - 1;
    int total = Bsz * P * K;
    int block = 256;

    if (K == 64) {
        hipLaunchKernelGGL(spline_fused_k64, dim3((total + block - 1) / block),
                           dim3(block), 0, stream, poses, timev, out,
                           n, total);
    } else {
        hipLaunchKernelGGL(lie_spline_mono, dim3((total + block - 1) / block),
                           dim3(block), 0, stream, poses, timev, out,
                           n, K, total);
    }
}

// Round 8
// 25.246 us; speedup vs baseline: 1.3815x; 1.3815x over previous
//
#include <hip/hip_runtime.h>
#include <hip/hip_bf16.h>

// Lie (SE3) cumulative B-spline evaluation, single fused kernel (K==64 path).
// Each 256-thread block = 4 waves = 4 consecutive (b,p) segments; lanes 0-11
// of wave 0 compute the block's 12 rel-logs in parallel (one per lane), shared
// via LDS. Quaternion composition; LDS-staged lane-contiguous nt stores.

__device__ __forceinline__ float frcp(float x) { return __builtin_amdgcn_rcpf(x); }

using f32x4 = __attribute__((ext_vector_type(4))) float;

struct Quat { float w, x, y, z; };

__device__ __forceinline__ void rel_log(const float* __restrict__ Ta,
                                        const float* __restrict__ Tb,
                                        float xi[6]) {
    float R[9];
#pragma unroll
    for (int i = 0; i < 3; ++i)
#pragma unroll
        for (int j = 0; j < 3; ++j)
            R[i * 3 + j] = Ta[0 * 4 + i] * Tb[0 * 4 + j] +
                           Ta[1 * 4 + i] * Tb[1 * 4 + j] +
                           Ta[2 * 4 + i] * Tb[2 * 4 + j];
    float dx = Tb[3] - Ta[3], dy = Tb[7] - Ta[7], dz = Tb[11] - Ta[11];
    float t0 = Ta[0] * dx + Ta[4] * dy + Ta[8] * dz;
    float t1 = Ta[1] * dx + Ta[5] * dy + Ta[9] * dz;
    float t2 = Ta[2] * dx + Ta[6] * dy + Ta[10] * dz;

    float tr = R[0] + R[4] + R[8];
    float cos_th = 0.5f * (tr - 1.0f);
    cos_th = fminf(fmaxf(cos_th, -1.0f + 1e-6f), 1.0f - 1e-6f);
    float th = acosf(cos_th);
    float s = sinf(th);
    float vx = 0.5f * (R[7] - R[5]);
    float vy = 0.5f * (R[2] - R[6]);
    float vz = 0.5f * (R[3] - R[1]);
    float f = th / s;
    float ox = f * vx, oy = f * vy, oz = f * vz;
    float th2 = th * th;
    float D;
    if (th < 0.05f)
        D = 1.0f / 12.0f + th2 / 720.0f;
    else
        D = 1.0f / th2 - (1.0f + cos_th) / (2.0f * th * s);

    float oo = ox * ox + oy * oy + oz * oz;
    float V00 = 1.0f + D * (ox * ox - oo);
    float V01 = 0.5f * oz + D * (ox * oy);
    float V02 = -0.5f * oy + D * (ox * oz);
    float V10 = -0.5f * oz + D * (ox * oy);
    float V11 = 1.0f + D * (oy * oy - oo);
    float V12 = 0.5f * ox + D * (oy * oz);
    float V20 = 0.5f * oy + D * (ox * oz);
    float V21 = -0.5f * ox + D * (oy * oz);
    float V22 = 1.0f + D * (oz * oz - oo);

    xi[0] = V00 * t0 + V01 * t1 + V02 * t2;
    xi[1] = V10 * t0 + V11 * t1 + V12 * t2;
    xi[2] = V20 * t0 + V21 * t1 + V22 * t2;
    xi[3] = ox; xi[4] = oy; xi[5] = oz;
}

// exp(w*xi) -> (quat, translation) with Rodrigues-form V application.
__device__ __forceinline__ void exp_qt(float wgt, const float* __restrict__ xi,
                                       Quat& q, float t[3]) {
    float nx = wgt * xi[0], ny = wgt * xi[1], nz = wgt * xi[2];
    float ox = wgt * xi[3], oy = wgt * xi[4], oz = wgt * xi[5];
    float th2 = ox * ox + oy * oy + oz * oz;
    bool small = th2 < 1e-8f;
    float th = sqrtf(th2);
    float rth = frcp(th);
    float sh, ch;
    __sincosf(0.5f * th, &sh, &ch);
    float rth2 = rth * rth;
    float sh2 = sh * sh;
    float sinth = 2.0f * sh * ch;
    float sfac = small ? 0.5f - th2 * (1.0f / 48.0f) : sh * rth;
    float B = small ? 0.5f - th2 * (1.0f / 24.0f) : (sh2 + sh2) * rth2;
    float C = small ? (1.0f / 6.0f) - th2 * (1.0f / 120.0f)
                    : (th - sinth) * rth2 * rth;
    q.w = ch; q.x = sfac * ox; q.y = sfac * oy; q.z = sfac * oz;
    float c1x = oy * nz - oz * ny;
    float c1y = oz * nx - ox * nz;
    float c1z = ox * ny - oy * nx;
    float c2x = oy * c1z - oz * c1y;
    float c2y = oz * c1x - ox * c1z;
    float c2z = ox * c1y - oy * c1x;
    t[0] = nx + B * c1x + C * c2x;
    t[1] = ny + B * c1y + C * c2y;
    t[2] = nz + B * c1z + C * c2z;
}

__device__ __forceinline__ Quat qmul(const Quat& a, const Quat& b) {
    Quat r;
    r.w = a.w * b.w - a.x * b.x - a.y * b.y - a.z * b.z;
    r.x = a.w * b.x + a.x * b.w + a.y * b.z - a.z * b.y;
    r.y = a.w * b.y - a.x * b.z + a.y * b.w + a.z * b.x;
    r.z = a.w * b.z + a.x * b.y - a.y * b.x + a.z * b.w;
    return r;
}

__device__ __forceinline__ void qrot(const Quat& q, const float v[3], float o[3]) {
    float ux = q.y * v[2] - q.z * v[1];
    float uy = q.z * v[0] - q.x * v[2];
    float uz = q.x * v[1] - q.y * v[0];
    float sx = q.w * ux + (q.y * uz - q.z * uy);
    float sy = q.w * uy + (q.z * ux - q.x * uz);
    float sz = q.w * uz + (q.x * uy - q.y * ux);
    o[0] = v[0] + 2.0f * sx;
    o[1] = v[1] + 2.0f * sy;
    o[2] = v[2] + 2.0f * sz;
}

__device__ __forceinline__ void q2m(const Quat& q, float M[9]) {
    float x2 = q.x + q.x, y2 = q.y + q.y, z2 = q.z + q.z;
    float xx = q.x * x2, yy = q.y * y2, zz = q.z * z2;
    float xy = q.x * y2, xz = q.x * z2, yz = q.y * z2;
    float wx = q.w * x2, wy = q.w * y2, wz = q.w * z2;
    M[0] = 1.0f - (yy + zz); M[1] = xy - wz;          M[2] = xz + wy;
    M[3] = xy + wz;          M[4] = 1.0f - (xx + zz); M[5] = yz - wx;
    M[6] = xz - wy;          M[7] = yz + wx;          M[8] = 1.0f - (xx + yy);
}

// Fused fast path: K == 64 (k = lane), (b,p) wave-uniform; block-shared logs.
__global__ void __launch_bounds__(256)
spline_block_k64(const float* __restrict__ poses,
                 const float* __restrict__ timev,
                 float* __restrict__ out,
                 int n, int total) {
    __shared__ f32x4 lds4[768];     // rows 0..2 of 256 matrices (row 3 const)
    __shared__ float ldsxi[12][8];  // 12 block-shared rel-logs (padded rows)

    int tid = threadIdx.x;
    int g = blockIdx.x * 256 + tid;
    bool fullBlock = (blockIdx.x + 1) * 256 <= total;
    bool active = g < total;
    int P = n - 1;
    int nbp = total >> 6;

    // Phase 1: lanes 0-11 of wave 0 compute the block's 12 rel-logs.
    if (tid < 12) {
        int w = tid / 3;            // which wave's segment
        int r = tid - 3 * w;        // which of its 3 logs
        int bp = blockIdx.x * 4 + w;
        if (bp < nbp) {
            int p = bp % P;
            int b = bp / P;
            int j = p + r;          // rel index j in [0, n]
            int ia = max(j - 1, 0);
            int ib = min(j, n - 1);
            const float* base = poses + (size_t)b * n * 16;
            float xi[6];
            rel_log(base + ia * 16, base + ib * 16, xi);
#pragma unroll
            for (int i = 0; i < 6; ++i) ldsxi[tid][i] = xi[i];
        }
    }
    __syncthreads();

    f32x4 r0, r1, r2;
    if (active) {
        int k = g & 63;
        int bp = __builtin_amdgcn_readfirstlane(g >> 6);
        int w = tid >> 6;
        int p = bp % P;
        int b = bp / P;

        const float* T0 = poses + ((size_t)b * n + max(p - 1, 0)) * 16;

        float xi01[6], xi12[6], xi23[6];
#pragma unroll
        for (int i = 0; i < 6; ++i) {
            xi01[i] = ldsxi[3 * w + 0][i];
            xi12[i] = ldsxi[3 * w + 1][i];
            xi23[i] = ldsxi[3 * w + 2][i];
        }

        float tt = timev[k];
        float t2 = tt * tt, t3 = t2 * tt;
        float w0 = (5.0f + 3.0f * tt - 3.0f * t2 + t3) * (1.0f / 6.0f);
        float w1 = (1.0f + 3.0f * tt + 3.0f * t2 - 2.0f * t3) * (1.0f / 6.0f);
        float w2 = t3 * (1.0f / 6.0f);

        Quat qa, qb, qc;
        float ta[3], tb[3], tc[3];
        exp_qt(w0, xi01, qa, ta);
        exp_qt(w1, xi12, qb, tb);
        exp_qt(w2, xi23, qc, tc);

        Quat qabc = qmul(qmul(qa, qb), qc);

        float u[3], v[3];
        qrot(qb, tc, u);
        u[0] += tb[0]; u[1] += tb[1]; u[2] += tb[2];
        qrot(qa, u, v);
        v[0] += ta[0]; v[1] += ta[1]; v[2] += ta[2];

        float M[9];
        q2m(qabc, M);

        float o[12];
#pragma unroll
        for (int i = 0; i < 3; ++i) {
            float a0 = T0[4 * i + 0], a1 = T0[4 * i + 1], a2 = T0[4 * i + 2];
            o[4 * i + 0] = a0 * M[0] + a1 * M[3] + a2 * M[6];
            o[4 * i + 1] = a0 * M[1] + a1 * M[4] + a2 * M[7];
            o[4 * i + 2] = a0 * M[2] + a1 * M[5] + a2 * M[8];
            o[4 * i + 3] = T0[4 * i + 3] + a0 * v[0] + a1 * v[1] + a2 * v[2];
        }
        r0 = (f32x4){o[0], o[1], o[2], o[3]};
        r1 = (f32x4){o[4], o[5], o[6], o[7]};
        r2 = (f32x4){o[8], o[9], o[10], o[11]};
    }

    if (fullBlock) {
        // Stage rows into LDS (lane-contiguous, conflict-free: 8 phases/wave).
        lds4[0 * 256 + tid] = r0;
        lds4[1 * 256 + tid] = r1;
        lds4[2 * 256 + tid] = r2;
        __syncthreads();
        // Cooperative contiguous store: float4 q = i*256+tid of this block's
        // 16 KB tile; q belongs to matrix q>>2, row q&3. Row 3 is constant.
        f32x4* outb = (f32x4*)out + (size_t)blockIdx.x * 1024;
        int r = tid & 3;
        int a = tid >> 2;
        const f32x4 last = (f32x4){0.0f, 0.0f, 0.0f, 1.0f};
#pragma unroll
        for (int i = 0; i < 4; ++i) {
            f32x4 val = (r == 3) ? last : lds4[r * 256 + 64 * i + a];
            __builtin_nontemporal_store(val, &outb[i * 256 + tid]);
        }
    } else if (active) {
        f32x4* o4 = (f32x4*)(out + (size_t)g * 16);
        o4[0] = r0;
        o4[1] = r1;
        o4[2] = r2;
        o4[3] = (f32x4){0.0f, 0.0f, 0.0f, 1.0f};
    }
}

// Generic fallback (matrix form), any K.
__device__ __forceinline__ void se3_exp_scaled(float sc, const float xi[6],
                                               float R[9], float t[3]) {
    float nx = sc * xi[0], ny = sc * xi[1], nz = sc * xi[2];
    float ox = sc * xi[3], oy = sc * xi[4], oz = sc * xi[5];
    float th2 = ox * ox + oy * oy + oz * oz;
    float A, B, C;
    if (th2 < 1e-8f) {
        A = 1.0f - th2 * (1.0f / 6.0f);
        B = 0.5f - th2 * (1.0f / 24.0f);
        C = 1.0f / 6.0f - th2 * (1.0f / 120.0f);
    } else {
        float th = sqrtf(th2);
        float sn, cs;
        __sincosf(th, &sn, &cs);
        float r = frcp(th);
        float r2 = r * r;
        A = sn * r;
        B = (1.0f - cs) * r2;
        C = (th - sn) * r2 * r;
    }
    float xx = ox * ox, yy = oy * oy, zz = oz * oz;
    float xy = ox * oy, xz = ox * oz, yz = oy * oz;
    R[0] = 1.0f + B * (xx - th2);
    R[1] = B * xy - A * oz;
    R[2] = B * xz + A * oy;
    R[3] = B * xy + A * oz;
    R[4] = 1.0f + B * (yy - th2);
    R[5] = B * yz - A * ox;
    R[6] = B * xz - A * oy;
    R[7] = B * yz + A * ox;
    R[8] = 1.0f + B * (zz - th2);
    float V00 = 1.0f + C * (xx - th2);
    float V01 = C * xy - B * oz;
    float V02 = C * xz + B * oy;
    float V10 = C * xy + B * oz;
    float V11 = 1.0f + C * (yy - th2);
    float V12 = C * yz - B * ox;
    float V20 = C * xz - B * oy;
    float V21 = C * yz + B * ox;
    float V22 = 1.0f + C * (zz - th2);
    t[0] = V00 * nx + V01 * ny + V02 * nz;
    t[1] = V10 * nx + V11 * ny + V12 * nz;
    t[2] = V20 * nx + V21 * ny + V22 * nz;
}

__device__ __forceinline__ void compose(const float R1[9], const float t1[3],
                                        const float R2[9], const float t2[3],
                                        float Ro[9], float to[3]) {
#pragma unroll
    for (int i = 0; i < 3; ++i) {
#pragma unroll
        for (int j = 0; j < 3; ++j)
            Ro[i * 3 + j] = R1[i * 3 + 0] * R2[0 * 3 + j] +
                            R1[i * 3 + 1] * R2[1 * 3 + j] +
                            R1[i * 3 + 2] * R2[2 * 3 + j];
        to[i] = R1[i * 3 + 0] * t2[0] + R1[i * 3 + 1] * t2[1] +
                R1[i * 3 + 2] * t2[2] + t1[i];
    }
}

__global__ void __launch_bounds__(256)
lie_spline_mono(const float* __restrict__ poses,
                const float* __restrict__ timev,
                float* __restrict__ out,
                int n, int K, int total) {
    int g = blockIdx.x * blockDim.x + threadIdx.x;
    if (g >= total) return;
    int P = n - 1;
    int k = g % K;
    int bp = g / K;
    int p = bp % P;
    int b = bp / P;
    int i0 = max(p - 1, 0);
    int i1 = p;
    int i2 = min(p + 1, n - 1);
    int i3 = min(p + 2, n - 1);
    const float* base = poses + (size_t)b * n * 16;
    const float *T0 = base + i0 * 16, *T1 = base + i1 * 16;
    const float *T2 = base + i2 * 16, *T3 = base + i3 * 16;
    float xi01[6], xi12[6], xi23[6];
    rel_log(T0, T1, xi01);
    rel_log(T1, T2, xi12);
    rel_log(T2, T3, xi23);
    float t = timev[k];
    float t2 = t * t, t3 = t2 * t;
    float w0 = (5.0f + 3.0f * t - 3.0f * t2 + t3) * (1.0f / 6.0f);
    float w1 = (1.0f + 3.0f * t + 3.0f * t2 - 2.0f * t3) * (1.0f / 6.0f);
    float w2 = t3 * (1.0f / 6.0f);
    float Ra[9], ta[3], Rb[9], tb[3], Rc[9], tc[3];
    se3_exp_scaled(w0, xi01, Ra, ta);
    se3_exp_scaled(w1, xi12, Rb, tb);
    se3_exp_scaled(w2, xi23, Rc, tc);
    float R0[9] = {T0[0], T0[1], T0[2], T0[4], T0[5], T0[6], T0[8], T0[9], T0[10]};
    float p0[3] = {T0[3], T0[7], T0[11]};
    float Rx[9], tx[3], Ry[9], ty[3], Rz[9], tz[3];
    compose(R0, p0, Ra, ta, Rx, tx);
    compose(Rx, tx, Rb, tb, Ry, ty);
    compose(Ry, ty, Rc, tc, Rz, tz);
    float4* o4 = (float4*)(out + (size_t)g * 16);
    o4[0] = make_float4(Rz[0], Rz[1], Rz[2], tz[0]);
    o4[1] = make_float4(Rz[3], Rz[4], Rz[5], tz[1]);
    o4[2] = make_float4(Rz[6], Rz[7], Rz[8], tz[2]);
    o4[3] = make_float4(0.0f, 0.0f, 0.0f, 1.0f);
}

extern "C" void kernel_launch(void* const* d_in, const int* in_sizes, int n_in,
                              void* d_out, int out_size, void* d_ws, size_t ws_size,
                              hipStream_t stream) {
    const float* poses = (const float*)d_in[0];
    const float* timev = (const float*)d_in[1];
    float* out = (float*)d_out;

    int K = in_sizes[1];
    int S = in_sizes[0] / 16;            // B * n
    int Q = out_size / (16 * K);         // B * (n-1)
    int Bsz = S - Q;                     // B
    int n = S / Bsz;

    int P = n - 1;
    int total = Bsz * P * K;
    int block = 256;

    if (K == 64) {
        hipLaunchKernelGGL(spline_block_k64, dim3((total + block - 1) / block),
                           dim3(block), 0, stream, poses, timev, out,
                           n, total);
    } else {
        hipLaunchKernelGGL(lie_spline_mono, dim3((total + block - 1) / block),
                           dim3(block), 0, stream, poses, timev, out,
                           n, K, total);
    }
}